// Round 4
// baseline (4022.533 us; speedup 1.0000x reference)
//
#include <hip/hip_runtime.h>
#include <hip/hip_bf16.h>

#define TT 200
#define UU 50
#define BB 8
#define DJ 1024   // D_JOINT
#define DE 512    // D_ENC / D_DEC
#define VV 1024
#define M_TOTAL (BB*TT*UU)   // 80000
#define MB 320               // M rows per block
#define NITER 32             // K / 32

typedef __bf16 bf16x8 __attribute__((ext_vector_type(8)));
typedef float f32x4 __attribute__((ext_vector_type(4)));

__device__ __forceinline__ float fast_tanh(float x) {
    float e = __expf(2.f * x);
    return 1.f - 2.f / (e + 1.f);
}

__device__ __forceinline__ bf16x8 tanh_pack8(float4 e0, float4 e1, float4 d0, float4 d1) {
    bf16x8 h;
    h[0] = (__bf16)fast_tanh(e0.x + d0.x); h[1] = (__bf16)fast_tanh(e0.y + d0.y);
    h[2] = (__bf16)fast_tanh(e0.z + d0.z); h[3] = (__bf16)fast_tanh(e0.w + d0.w);
    h[4] = (__bf16)fast_tanh(e1.x + d1.x); h[5] = (__bf16)fast_tanh(e1.y + d1.y);
    h[6] = (__bf16)fast_tanh(e1.z + d1.z); h[7] = (__bf16)fast_tanh(e1.w + d1.w);
    return h;
}

__device__ __forceinline__ void gload_lds16(const unsigned short* g, unsigned short* l) {
    __builtin_amdgcn_global_load_lds(
        (const __attribute__((address_space(1))) unsigned int*)(const void*)g,
        (__attribute__((address_space(3))) unsigned int*)(void*)l, 16, 0, 0);
}

// ---------- kernel 1: W_fc fp32 [n][k] -> bf16 granule-major [gk][n] ----------
__global__ void k_wfct(const float* __restrict__ w, unsigned short* __restrict__ o) {
    const int G = blockIdx.x * 256 + threadIdx.x;   // granule id, 131072 total
    const int gk = G >> 10, n = G & 1023;
    const float* src = w + (size_t)n * DJ + gk * 8;
    float4 a = *(const float4*)(src);
    float4 b = *(const float4*)(src + 4);
    bf16x8 h;
    h[0] = (__bf16)a.x; h[1] = (__bf16)a.y; h[2] = (__bf16)a.z; h[3] = (__bf16)a.w;
    h[4] = (__bf16)b.x; h[5] = (__bf16)b.y; h[6] = (__bf16)b.z; h[7] = (__bf16)b.w;
    *(bf16x8*)(o + (size_t)G * 8) = h;
}

// ---------- kernel 2: both projections, one grid ----------
// blocks 0..99: enc (1600 rows); blocks 100..124: dec (400 rows)
__global__ __launch_bounds__(256) void k_proj2(const float* __restrict__ enc,
                                               const float* __restrict__ dec,
                                               const float* __restrict__ W_enc,
                                               const float* __restrict__ b_enc,
                                               const float* __restrict__ W_dec,
                                               const float* __restrict__ b_dec,
                                               float* __restrict__ encp,
                                               float* __restrict__ decp) {
    __shared__ float in_s[16][DE];
    const bool isDec = blockIdx.x >= 100;
    const float* in  = isDec ? dec   : enc;
    const float* W   = isDec ? W_dec : W_enc;
    const float* bia = isDec ? b_dec : b_enc;
    float* out       = isDec ? decp  : encp;
    const int m0 = (isDec ? (blockIdx.x - 100) : blockIdx.x) * 16;
    const int tid = threadIdx.x;
    #pragma unroll
    for (int it = 0; it < 8; ++it) {
        int idx = tid + it * 256;
        int r = idx >> 7, c = (idx & 127) << 2;
        *(float4*)&in_s[r][c] = *(const float4*)(in + (size_t)(m0 + r) * DE + c);
    }
    __syncthreads();
    const int j = blockIdx.y * 256 + tid;
    const float4* wr = (const float4*)(W + (size_t)j * DE);
    float acc[16];
    #pragma unroll
    for (int r = 0; r < 16; ++r) acc[r] = 0.f;
    for (int d4 = 0; d4 < DE / 4; ++d4) {
        float4 w = wr[d4];
        #pragma unroll
        for (int r = 0; r < 16; ++r) {
            float4 x = *(const float4*)&in_s[r][d4 << 2];
            acc[r] += x.x * w.x + x.y * w.y + x.z * w.z + x.w * w.w;
        }
    }
    float bv = bia[j];
    #pragma unroll
    for (int r = 0; r < 16; ++r)
        out[(size_t)(m0 + r) * DJ + j] = acc[r] + bv;
}

// ---------- kernel 3: fused tanh(enc+dec) @ W_fc^T + b_fc -> log_softmax ----------
// 1024 threads (16 waves, 4M x 4N). Block: 320 M x 1024 N, K in 32-chunks.
// Bs double-buffered (128 KB), gload_lds coalesced from granule-major W_fc.
// As single-buffered (20 KB): per-thread on-the-fly tanh(enc[t]+dec[u]) granule staging
//   (enc/dec source rows are few per block -> L1-served).
// Wave = 80M x 256N: 5x16 fragments of 16x16x32, acc = 320 f32 (AGPR+VGPR).
__global__ __launch_bounds__(1024, 4) void k_joint(const float* __restrict__ encp,
                                                   const float* __restrict__ decp,
                                                   const unsigned short* __restrict__ wfcg,
                                                   const float* __restrict__ bfc,
                                                   float* __restrict__ out) {
    __shared__ unsigned short Bs[2][4096 * 8];   // 128 KB
    __shared__ unsigned short As[1280 * 8];      // 20 KB, granule (gk,m) at gk*320+m
    __shared__ float red[4][MB];                 // 5 KB

    const int tid = threadIdx.x;
    const int wave = tid >> 6, lane = tid & 63;
    const int wm = wave >> 2, wn = wave & 3;
    const int g = lane >> 4, ln = lane & 15;
    const int m0 = blockIdx.x * MB;

    // ---- staging granule assignments: G0 = tid; G1 = 1024+tid (tid<256) ----
    const int gk0 = tid / MB;            // 0..3
    const int ml0 = tid - gk0 * MB;
    int mg = m0 + ml0;
    int b = mg / (TT * UU);
    int rem = mg - b * (TT * UU);
    int t = rem / UU;
    int u = rem - t * UU;
    const float* er0 = encp + (size_t)(b * TT + t) * DJ + gk0 * 8;
    const float* dr0 = decp + (size_t)(b * UU + u) * DJ + gk0 * 8;

    const bool two = (tid < 256);        // waves 0..3 (wave-uniform)
    const float* er1 = er0;
    const float* dr1 = dr0;
    if (two) {
        int ml1 = 64 + tid;              // G1 = 1024+tid -> gk=3, m=64+tid
        int mg1 = m0 + ml1;
        int b1 = mg1 / (TT * UU);
        int r1 = mg1 - b1 * (TT * UU);
        int t1 = r1 / UU;
        int u1 = r1 - t1 * UU;
        er1 = encp + (size_t)(b1 * TT + t1) * DJ + 3 * 8;
        dr1 = decp + (size_t)(b1 * UU + u1) * DJ + 3 * 8;
    }

    f32x4 acc[5][16];
    #pragma unroll
    for (int mf = 0; mf < 5; ++mf)
        #pragma unroll
        for (int nf = 0; nf < 16; ++nf)
            acc[mf][nf] = (f32x4){0.f, 0.f, 0.f, 0.f};

    // ---- prologue: chunk 0 ----
    #pragma unroll
    for (int r = 0; r < 4; ++r)
        gload_lds16(wfcg + (size_t)(r * 1024 + tid) * 8, &Bs[0][(r * 1024 + tid) * 8]);
    {
        float4 e0 = *(const float4*)(er0);
        float4 e1 = *(const float4*)(er0 + 4);
        float4 d0 = *(const float4*)(dr0);
        float4 d1 = *(const float4*)(dr0 + 4);
        *(bf16x8*)&As[tid * 8] = tanh_pack8(e0, e1, d0, d1);
        if (two) {
            float4 f0 = *(const float4*)(er1);
            float4 f1 = *(const float4*)(er1 + 4);
            float4 h0 = *(const float4*)(dr1);
            float4 h1 = *(const float4*)(dr1 + 4);
            *(bf16x8*)&As[(1024 + tid) * 8] = tanh_pack8(f0, f1, h0, h1);
        }
    }
    __syncthreads();

    // ---- main loop ----
    for (int it = 0; it < NITER; ++it) {
        const int cur = it & 1, nxt = cur ^ 1;
        // read A-frags for this chunk, then free As for overwrite
        bf16x8 af[5];
        #pragma unroll
        for (int mf = 0; mf < 5; ++mf)
            af[mf] = *(const bf16x8*)&As[(g * MB + wm * 80 + mf * 16 + ln) * 8];
        __syncthreads();   // barrier1: all A-reads done; As writable; no vmem outstanding

        const bool notlast = (it < NITER - 1);
        float4 e0, e1, d0, d1, f0, f1, h0, h1;
        if (notlast) {
            const unsigned short* src = wfcg + (size_t)(it + 1) * 4096 * 8;
            #pragma unroll
            for (int r = 0; r < 4; ++r)
                gload_lds16(src + (size_t)(r * 1024 + tid) * 8, &Bs[nxt][(r * 1024 + tid) * 8]);
            const int k1 = (it + 1) * 32;
            e0 = *(const float4*)(er0 + k1);
            e1 = *(const float4*)(er0 + k1 + 4);
            d0 = *(const float4*)(dr0 + k1);
            d1 = *(const float4*)(dr0 + k1 + 4);
            if (two) {
                f0 = *(const float4*)(er1 + k1);
                f1 = *(const float4*)(er1 + k1 + 4);
                h0 = *(const float4*)(dr1 + k1);
                h1 = *(const float4*)(dr1 + k1 + 4);
            }
        }
        #pragma unroll
        for (int nf = 0; nf < 16; ++nf) {
            bf16x8 bfr = *(const bf16x8*)&Bs[cur][(g * 1024 + wn * 256 + nf * 16 + ln) * 8];
            #pragma unroll
            for (int mf = 0; mf < 5; ++mf)
                acc[mf][nf] = __builtin_amdgcn_mfma_f32_16x16x32_bf16(af[mf], bfr, acc[mf][nf], 0, 0, 0);
        }
        if (notlast) {
            *(bf16x8*)&As[tid * 8] = tanh_pack8(e0, e1, d0, d1);
            if (two)
                *(bf16x8*)&As[(1024 + tid) * 8] = tanh_pack8(f0, f1, h0, h1);
        }
        __syncthreads();   // barrier2: drains gload_lds (Bs[nxt]) + As writes
    }

    // ---- fused log_softmax epilogue ----
    // C frag (mf,nf): row = wm*80 + mf*16 + g*4 + j, col = wn*256 + nf*16 + ln
    #pragma unroll
    for (int nf = 0; nf < 16; ++nf) {
        float bv = bfc[wn * 256 + nf * 16 + ln];
        #pragma unroll
        for (int mf = 0; mf < 5; ++mf)
            #pragma unroll
            for (int j = 0; j < 4; ++j)
                acc[mf][nf][j] += bv;
    }

    // row max: lane-local over nf, 16-lane shuffle, cross-wave (4 N-waves) via red
    float rmx[5][4];
    #pragma unroll
    for (int mf = 0; mf < 5; ++mf)
        #pragma unroll
        for (int j = 0; j < 4; ++j) {
            float mx = -3.0e38f;
            #pragma unroll
            for (int nf = 0; nf < 16; ++nf) mx = fmaxf(mx, acc[mf][nf][j]);
            #pragma unroll
            for (int s = 1; s < 16; s <<= 1) mx = fmaxf(mx, __shfl_xor(mx, s));
            rmx[mf][j] = mx;
        }
    if (ln == 0) {
        #pragma unroll
        for (int mf = 0; mf < 5; ++mf)
            #pragma unroll
            for (int j = 0; j < 4; ++j)
                red[wn][wm * 80 + mf * 16 + g * 4 + j] = rmx[mf][j];
    }
    __syncthreads();
    #pragma unroll
    for (int mf = 0; mf < 5; ++mf)
        #pragma unroll
        for (int j = 0; j < 4; ++j) {
            const int r = wm * 80 + mf * 16 + g * 4 + j;
            rmx[mf][j] = fmaxf(fmaxf(red[0][r], red[1][r]), fmaxf(red[2][r], red[3][r]));
        }
    __syncthreads();   // red reused for sums

    float rsm[5][4];
    #pragma unroll
    for (int mf = 0; mf < 5; ++mf)
        #pragma unroll
        for (int j = 0; j < 4; ++j) {
            float s = 0.f;
            #pragma unroll
            for (int nf = 0; nf < 16; ++nf) s += __expf(acc[mf][nf][j] - rmx[mf][j]);
            #pragma unroll
            for (int t2 = 1; t2 < 16; t2 <<= 1) s += __shfl_xor(s, t2);
            rsm[mf][j] = s;
        }
    if (ln == 0) {
        #pragma unroll
        for (int mf = 0; mf < 5; ++mf)
            #pragma unroll
            for (int j = 0; j < 4; ++j)
                red[wn][wm * 80 + mf * 16 + g * 4 + j] = rsm[mf][j];
    }
    __syncthreads();
    #pragma unroll
    for (int mf = 0; mf < 5; ++mf)
        #pragma unroll
        for (int j = 0; j < 4; ++j) {
            const int r = wm * 80 + mf * 16 + g * 4 + j;
            const float s = red[0][r] + red[1][r] + red[2][r] + red[3][r];
            const float lse = rmx[mf][j] + __logf(s);
            float* op = out + (size_t)(m0 + r) * VV + wn * 256 + ln;
            #pragma unroll
            for (int nf = 0; nf < 16; ++nf)
                __builtin_nontemporal_store(acc[mf][nf][j] - lse, op + nf * 16);
        }
}

extern "C" void kernel_launch(void* const* d_in, const int* in_sizes, int n_in,
                              void* d_out, int out_size, void* d_ws, size_t ws_size,
                              hipStream_t stream) {
    const float* enc   = (const float*)d_in[0];
    const float* dec   = (const float*)d_in[1];
    const float* W_enc = (const float*)d_in[2];
    const float* b_enc = (const float*)d_in[3];
    const float* W_dec = (const float*)d_in[4];
    const float* b_dec = (const float*)d_in[5];
    const float* W_fc  = (const float*)d_in[6];
    const float* b_fc  = (const float*)d_in[7];
    float* out = (float*)d_out;

    float* encp = (float*)d_ws;                              // 1600*1024 f32
    float* decp = encp + (size_t)BB * TT * DJ;               //  400*1024 f32
    unsigned short* wfcg = (unsigned short*)(decp + (size_t)BB * UU * DJ);  // 2 MB bf16, granule-major

    k_wfct<<<(VV * DJ) / (256 * 8), 256, 0, stream>>>(W_fc, wfcg);
    k_proj2<<<dim3(125, DJ / 256), 256, 0, stream>>>(enc, dec, W_enc, b_enc, W_dec, b_dec, encp, decp);
    k_joint<<<M_TOTAL / MB, 1024, 0, stream>>>(encp, decp, wfcg, b_fc, out);
}

// Round 5
// 404.139 us; speedup vs baseline: 9.9534x; 9.9534x over previous
//
#include <hip/hip_runtime.h>
#include <hip/hip_bf16.h>

#define TT 200
#define UU 50
#define BB 8
#define DJ 1024   // D_JOINT
#define DE 512    // D_ENC / D_DEC
#define VV 1024
#define M_TOTAL (BB*TT*UU)   // 80000
#define MB 80                // M rows per block
#define NITER 32             // K / 32

typedef __bf16 bf16x8 __attribute__((ext_vector_type(8)));
typedef float f32x4 __attribute__((ext_vector_type(4)));

__device__ __forceinline__ float fast_tanh(float x) {
    float e = __expf(2.f * x);
    return 1.f - 2.f / (e + 1.f);
}

__device__ __forceinline__ bf16x8 tanh_pack8(float4 e0, float4 e1, float4 d0, float4 d1) {
    bf16x8 h;
    h[0] = (__bf16)fast_tanh(e0.x + d0.x); h[1] = (__bf16)fast_tanh(e0.y + d0.y);
    h[2] = (__bf16)fast_tanh(e0.z + d0.z); h[3] = (__bf16)fast_tanh(e0.w + d0.w);
    h[4] = (__bf16)fast_tanh(e1.x + d1.x); h[5] = (__bf16)fast_tanh(e1.y + d1.y);
    h[6] = (__bf16)fast_tanh(e1.z + d1.z); h[7] = (__bf16)fast_tanh(e1.w + d1.w);
    return h;
}

__device__ __forceinline__ void gload_lds16(const unsigned short* g, unsigned short* l) {
    __builtin_amdgcn_global_load_lds(
        (const __attribute__((address_space(1))) unsigned int*)(const void*)g,
        (__attribute__((address_space(3))) unsigned int*)(void*)l, 16, 0, 0);
}

// ---------- kernel 1: W_fc fp32 [n][k] -> bf16 granule-major [gk][n] ----------
__global__ void k_wfct(const float* __restrict__ w, unsigned short* __restrict__ o) {
    const int G = blockIdx.x * 256 + threadIdx.x;   // granule id, 131072 total
    const int gk = G >> 10, n = G & 1023;
    const float* src = w + (size_t)n * DJ + gk * 8;
    float4 a = *(const float4*)(src);
    float4 b = *(const float4*)(src + 4);
    bf16x8 h;
    h[0] = (__bf16)a.x; h[1] = (__bf16)a.y; h[2] = (__bf16)a.z; h[3] = (__bf16)a.w;
    h[4] = (__bf16)b.x; h[5] = (__bf16)b.y; h[6] = (__bf16)b.z; h[7] = (__bf16)b.w;
    *(bf16x8*)(o + (size_t)G * 8) = h;
}

// ---------- kernel 2: both projections, one grid ----------
__global__ __launch_bounds__(256) void k_proj2(const float* __restrict__ enc,
                                               const float* __restrict__ dec,
                                               const float* __restrict__ W_enc,
                                               const float* __restrict__ b_enc,
                                               const float* __restrict__ W_dec,
                                               const float* __restrict__ b_dec,
                                               float* __restrict__ encp,
                                               float* __restrict__ decp) {
    __shared__ float in_s[16][DE];
    const bool isDec = blockIdx.x >= 100;
    const float* in  = isDec ? dec   : enc;
    const float* W   = isDec ? W_dec : W_enc;
    const float* bia = isDec ? b_dec : b_enc;
    float* out       = isDec ? decp  : encp;
    const int m0 = (isDec ? (blockIdx.x - 100) : blockIdx.x) * 16;
    const int tid = threadIdx.x;
    #pragma unroll
    for (int it = 0; it < 8; ++it) {
        int idx = tid + it * 256;
        int r = idx >> 7, c = (idx & 127) << 2;
        *(float4*)&in_s[r][c] = *(const float4*)(in + (size_t)(m0 + r) * DE + c);
    }
    __syncthreads();
    const int j = blockIdx.y * 256 + tid;
    const float4* wr = (const float4*)(W + (size_t)j * DE);
    float acc[16];
    #pragma unroll
    for (int r = 0; r < 16; ++r) acc[r] = 0.f;
    for (int d4 = 0; d4 < DE / 4; ++d4) {
        float4 w = wr[d4];
        #pragma unroll
        for (int r = 0; r < 16; ++r) {
            float4 x = *(const float4*)&in_s[r][d4 << 2];
            acc[r] += x.x * w.x + x.y * w.y + x.z * w.z + x.w * w.w;
        }
    }
    float bv = bia[j];
    #pragma unroll
    for (int r = 0; r < 16; ++r)
        out[(size_t)(m0 + r) * DJ + j] = acc[r] + bv;
}

// ---------- kernel 3: fused tanh(enc+dec) @ W_fc^T + b_fc -> log_softmax ----------
// 512 threads (8 waves). Block: 80 M x 1024 N. K-chunks processed in STAGGERED
// order (it + blockIdx.x) % 32 so concurrent CUs hit different L2 banks.
// Bs double-buffered (128 KB), coalesced gload_lds from granule-major W_fc.
// A (tanh) reg-staged by threads 0..319 as [gk][m] granules, double-buffered.
// C stored nontemporal (evict-first) to keep W_fc L2-resident.
__global__ __launch_bounds__(512, 2) void k_joint(const float* __restrict__ encp,
                                                  const float* __restrict__ decp,
                                                  const unsigned short* __restrict__ wfcg,
                                                  const float* __restrict__ bfc,
                                                  float* __restrict__ out) {
    __shared__ unsigned short Bs[2][4096 * 8];   // 128 KB
    __shared__ unsigned short As[2][320 * 8];    // 10 KB
    __shared__ float red[8][MB];                 // 2.5 KB

    const int tid = threadIdx.x;
    const int wave = tid >> 6, lane = tid & 63;
    const int g = lane >> 4, ln = lane & 15;
    const int bid = blockIdx.x;
    const int m0 = bid * MB;

    // A staging role: threads 0..319 (waves 0..4), one granule (gk, m) each
    const bool aRole = (tid < 320);
    const float *er = encp, *dr = decp;
    int agran = 0;
    if (aRole) {
        const int m = tid % MB;
        const int gk = tid / MB;
        const int mrow = m0 + m;
        const int b = mrow / (TT * UU);
        const int rem = mrow - b * (TT * UU);
        const int t = rem / UU;
        const int u = rem - t * UU;
        er = encp + (size_t)(b * TT + t) * DJ + gk * 8;
        dr = decp + (size_t)(b * UU + u) * DJ + gk * 8;
        agran = gk * MB + m;
    }

    f32x4 acc[5][8];
    #pragma unroll
    for (int mf = 0; mf < 5; ++mf)
        #pragma unroll
        for (int nf = 0; nf < 8; ++nf)
            acc[mf][nf] = (f32x4){0.f, 0.f, 0.f, 0.f};

    // ---- prologue: stage chunk (bid%32) into buf 0 ----
    {
        const int kb0 = bid & 31;
        if (aRole) {
            const int ko = kb0 * 32;
            float4 e0 = *(const float4*)(er + ko);
            float4 e1 = *(const float4*)(er + ko + 4);
            float4 d0 = *(const float4*)(dr + ko);
            float4 d1 = *(const float4*)(dr + ko + 4);
            *(bf16x8*)&As[0][agran * 8] = tanh_pack8(e0, e1, d0, d1);
        }
        const unsigned short* src = wfcg + (size_t)kb0 * 4096 * 8;
        #pragma unroll
        for (int r = 0; r < 8; ++r)
            gload_lds16(src + (size_t)(r * 512 + tid) * 8, &Bs[0][(r * 512 + wave * 64) * 8]);
    }
    __syncthreads();

    // ---- main loop: 2-phase double-buffered, staggered K order ----
    for (int it = 0; it < NITER; ++it) {
        const int cur = it & 1, nxt = cur ^ 1;
        const bool notlast = (it < NITER - 1);
        float4 e0, e1, d0, d1;
        if (notlast) {
            const int kb = (it + 1 + bid) & 31;
            // A-globals FIRST (so tanh below waits only on these, not on B drain)
            if (aRole) {
                const int ko = kb * 32;
                e0 = *(const float4*)(er + ko);
                e1 = *(const float4*)(er + ko + 4);
                d0 = *(const float4*)(dr + ko);
                d1 = *(const float4*)(dr + ko + 4);
            }
            const unsigned short* src = wfcg + (size_t)kb * 4096 * 8;
            #pragma unroll
            for (int r = 0; r < 8; ++r)
                gload_lds16(src + (size_t)(r * 512 + tid) * 8, &Bs[nxt][(r * 512 + wave * 64) * 8]);
        }
        bf16x8 af[5];
        #pragma unroll
        for (int mf = 0; mf < 5; ++mf)
            af[mf] = *(const bf16x8*)&As[cur][(g * MB + mf * 16 + ln) * 8];
        #pragma unroll
        for (int nf = 0; nf < 8; ++nf) {
            bf16x8 bfr = *(const bf16x8*)&Bs[cur][(g * 1024 + wave * 128 + nf * 16 + ln) * 8];
            #pragma unroll
            for (int mf = 0; mf < 5; ++mf)
                acc[mf][nf] = __builtin_amdgcn_mfma_f32_16x16x32_bf16(af[mf], bfr, acc[mf][nf], 0, 0, 0);
        }
        if (notlast && aRole)
            *(bf16x8*)&As[nxt][agran * 8] = tanh_pack8(e0, e1, d0, d1);
        __syncthreads();
    }

    // ---- fused log_softmax epilogue ----
    // C frag (mf,nf): row = mf*16 + g*4 + j, col = wave*128 + nf*16 + ln
    float bv[8];
    #pragma unroll
    for (int nf = 0; nf < 8; ++nf) bv[nf] = bfc[wave * 128 + nf * 16 + ln];
    #pragma unroll
    for (int mf = 0; mf < 5; ++mf)
        #pragma unroll
        for (int nf = 0; nf < 8; ++nf)
            #pragma unroll
            for (int j = 0; j < 4; ++j)
                acc[mf][nf][j] += bv[nf];

    float rmx[5][4];
    #pragma unroll
    for (int mf = 0; mf < 5; ++mf)
        #pragma unroll
        for (int j = 0; j < 4; ++j) {
            float mx = -3.0e38f;
            #pragma unroll
            for (int nf = 0; nf < 8; ++nf) mx = fmaxf(mx, acc[mf][nf][j]);
            #pragma unroll
            for (int s = 1; s < 16; s <<= 1) mx = fmaxf(mx, __shfl_xor(mx, s));
            rmx[mf][j] = mx;
        }
    if (ln == 0) {
        #pragma unroll
        for (int mf = 0; mf < 5; ++mf)
            #pragma unroll
            for (int j = 0; j < 4; ++j)
                red[wave][mf * 16 + g * 4 + j] = rmx[mf][j];
    }
    __syncthreads();
    #pragma unroll
    for (int mf = 0; mf < 5; ++mf)
        #pragma unroll
        for (int j = 0; j < 4; ++j) {
            const int r = mf * 16 + g * 4 + j;
            float mx = red[0][r];
            #pragma unroll
            for (int w = 1; w < 8; ++w) mx = fmaxf(mx, red[w][r]);
            rmx[mf][j] = mx;
        }
    __syncthreads();   // red reused for sums

    float rsm[5][4];
    #pragma unroll
    for (int mf = 0; mf < 5; ++mf)
        #pragma unroll
        for (int j = 0; j < 4; ++j) {
            float s = 0.f;
            #pragma unroll
            for (int nf = 0; nf < 8; ++nf) s += __expf(acc[mf][nf][j] - rmx[mf][j]);
            #pragma unroll
            for (int t2 = 1; t2 < 16; t2 <<= 1) s += __shfl_xor(s, t2);
            rsm[mf][j] = s;
        }
    if (ln == 0) {
        #pragma unroll
        for (int mf = 0; mf < 5; ++mf)
            #pragma unroll
            for (int j = 0; j < 4; ++j)
                red[wave][mf * 16 + g * 4 + j] = rsm[mf][j];
    }
    __syncthreads();
    #pragma unroll
    for (int mf = 0; mf < 5; ++mf)
        #pragma unroll
        for (int j = 0; j < 4; ++j) {
            const int r = mf * 16 + g * 4 + j;
            float s = 0.f;
            #pragma unroll
            for (int w = 0; w < 8; ++w) s += red[w][r];
            const float lse = rmx[mf][j] + __logf(s);
            float* op = out + (size_t)(m0 + r) * VV + wave * 128 + ln;
            #pragma unroll
            for (int nf = 0; nf < 8; ++nf)
                __builtin_nontemporal_store(acc[mf][nf][j] - lse, op + nf * 16);
        }
}

extern "C" void kernel_launch(void* const* d_in, const int* in_sizes, int n_in,
                              void* d_out, int out_size, void* d_ws, size_t ws_size,
                              hipStream_t stream) {
    const float* enc   = (const float*)d_in[0];
    const float* dec   = (const float*)d_in[1];
    const float* W_enc = (const float*)d_in[2];
    const float* b_enc = (const float*)d_in[3];
    const float* W_dec = (const float*)d_in[4];
    const float* b_dec = (const float*)d_in[5];
    const float* W_fc  = (const float*)d_in[6];
    const float* b_fc  = (const float*)d_in[7];
    float* out = (float*)d_out;

    float* encp = (float*)d_ws;                              // 1600*1024 f32
    float* decp = encp + (size_t)BB * TT * DJ;               //  400*1024 f32
    unsigned short* wfcg = (unsigned short*)(decp + (size_t)BB * UU * DJ);  // 2 MB bf16, granule-major

    k_wfct<<<(VV * DJ) / (256 * 8), 256, 0, stream>>>(W_fc, wfcg);
    k_proj2<<<dim3(125, DJ / 256), 256, 0, stream>>>(enc, dec, W_enc, b_enc, W_dec, b_dec, encp, decp);
    k_joint<<<M_TOTAL / MB, 512, 0, stream>>>(encp, decp, wfcg, b_fc, out);
}

// Round 6
// 402.032 us; speedup vs baseline: 10.0055x; 1.0052x over previous
//
#include <hip/hip_runtime.h>
#include <hip/hip_bf16.h>
#include <hip/hip_fp8.h>

#define TT 200
#define UU 50
#define BB 8
#define DJ 1024   // D_JOINT
#define DE 512    // D_ENC / D_DEC
#define VV 1024
#define M_TOTAL (BB*TT*UU)   // 80000
#define MB 80                // M rows per block
#define NITER 32             // K / 32
#define WINV (1.0f/32.0f)    // undo W_fc fp8 pre-scale

typedef float f32x4 __attribute__((ext_vector_type(4)));

__device__ __forceinline__ float fast_tanh(float x) {
    float e = __expf(2.f * x);
    return 1.f - 2.f / (e + 1.f);
}

__device__ __forceinline__ unsigned char f2fp8(float x) {
    return __hip_fp8_e4m3(x).__x;   // OCP e4m3, HW cvt, satfinite
}

__device__ __forceinline__ unsigned long long tanh_pack_fp8(float4 e0, float4 e1, float4 d0, float4 d1) {
    unsigned long long r;
    r  = (unsigned long long)f2fp8(fast_tanh(e0.x + d0.x));
    r |= (unsigned long long)f2fp8(fast_tanh(e0.y + d0.y)) << 8;
    r |= (unsigned long long)f2fp8(fast_tanh(e0.z + d0.z)) << 16;
    r |= (unsigned long long)f2fp8(fast_tanh(e0.w + d0.w)) << 24;
    r |= (unsigned long long)f2fp8(fast_tanh(e1.x + d1.x)) << 32;
    r |= (unsigned long long)f2fp8(fast_tanh(e1.y + d1.y)) << 40;
    r |= (unsigned long long)f2fp8(fast_tanh(e1.z + d1.z)) << 48;
    r |= (unsigned long long)f2fp8(fast_tanh(e1.w + d1.w)) << 56;
    return r;
}

__device__ __forceinline__ void gload_lds16(const unsigned char* g, unsigned char* l) {
    __builtin_amdgcn_global_load_lds(
        (const __attribute__((address_space(1))) unsigned int*)(const void*)g,
        (__attribute__((address_space(3))) unsigned int*)(void*)l, 16, 0, 0);
}

// ---------- kernel 1: W_fc fp32 [n][k] -> fp8 e4m3 (x32 scaled) granule-major [gk][n] ----------
// granule (n, gk) = W_fc[n][gk*8 .. gk*8+8) * 32 as 8 fp8 bytes at o + (gk*1024+n)*8
__global__ void k_wfct(const float* __restrict__ w, unsigned char* __restrict__ o) {
    const int G = blockIdx.x * 256 + threadIdx.x;   // granule id, 131072 total
    const int gk = G >> 10, n = G & 1023;
    const float* src = w + (size_t)n * DJ + gk * 8;
    float4 a = *(const float4*)(src);
    float4 b = *(const float4*)(src + 4);
    unsigned long long r;
    r  = (unsigned long long)f2fp8(a.x * 32.f);
    r |= (unsigned long long)f2fp8(a.y * 32.f) << 8;
    r |= (unsigned long long)f2fp8(a.z * 32.f) << 16;
    r |= (unsigned long long)f2fp8(a.w * 32.f) << 24;
    r |= (unsigned long long)f2fp8(b.x * 32.f) << 32;
    r |= (unsigned long long)f2fp8(b.y * 32.f) << 40;
    r |= (unsigned long long)f2fp8(b.z * 32.f) << 48;
    r |= (unsigned long long)f2fp8(b.w * 32.f) << 56;
    *(unsigned long long*)(o + (size_t)G * 8) = r;
}

// ---------- kernel 2: both projections, one grid ----------
__global__ __launch_bounds__(256) void k_proj2(const float* __restrict__ enc,
                                               const float* __restrict__ dec,
                                               const float* __restrict__ W_enc,
                                               const float* __restrict__ b_enc,
                                               const float* __restrict__ W_dec,
                                               const float* __restrict__ b_dec,
                                               float* __restrict__ encp,
                                               float* __restrict__ decp) {
    __shared__ float in_s[16][DE];
    const bool isDec = blockIdx.x >= 100;
    const float* in  = isDec ? dec   : enc;
    const float* W   = isDec ? W_dec : W_enc;
    const float* bia = isDec ? b_dec : b_enc;
    float* out       = isDec ? decp  : encp;
    const int m0 = (isDec ? (blockIdx.x - 100) : blockIdx.x) * 16;
    const int tid = threadIdx.x;
    #pragma unroll
    for (int it = 0; it < 8; ++it) {
        int idx = tid + it * 256;
        int r = idx >> 7, c = (idx & 127) << 2;
        *(float4*)&in_s[r][c] = *(const float4*)(in + (size_t)(m0 + r) * DE + c);
    }
    __syncthreads();
    const int j = blockIdx.y * 256 + tid;
    const float4* wr = (const float4*)(W + (size_t)j * DE);
    float acc[16];
    #pragma unroll
    for (int r = 0; r < 16; ++r) acc[r] = 0.f;
    for (int d4 = 0; d4 < DE / 4; ++d4) {
        float4 w = wr[d4];
        #pragma unroll
        for (int r = 0; r < 16; ++r) {
            float4 x = *(const float4*)&in_s[r][d4 << 2];
            acc[r] += x.x * w.x + x.y * w.y + x.z * w.z + x.w * w.w;
        }
    }
    float bv = bia[j];
    #pragma unroll
    for (int r = 0; r < 16; ++r)
        out[(size_t)(m0 + r) * DJ + j] = acc[r] + bv;
}

// ---------- kernel 3: fused tanh(enc+dec) @ W_fc^T + b_fc -> log_softmax ----------
// 512 threads (8 waves). Block: 80 M x 1024 N. fp8 e4m3 GEMM (16x16x32_fp8_fp8).
// Bs TRIPLE-buffered 32 KB chunks; counted-vmcnt pipeline: issue chunk t+2 at iter t,
// per-iter wait = vmcnt(4) (B(t+1) stays in flight across the barrier) -- never 0 mid-loop.
// A (tanh->fp8) staged by threads 0..319 (waves 0-4), triple-buffered, loads 1 ahead.
// K-chunk order staggered by blockIdx. C stored nontemporal.
__global__ __launch_bounds__(512, 2) void k_joint(const float* __restrict__ encp,
                                                  const float* __restrict__ decp,
                                                  const unsigned char* __restrict__ wfc8,
                                                  const float* __restrict__ bfc,
                                                  float* __restrict__ out) {
    __shared__ unsigned char Bs[3][32768];   // 96 KB: [gk 0..3][n 0..1023] 8B granules
    __shared__ unsigned char As[3][2560];    // 7.5 KB: [gk 0..3][m 0..79] 8B granules
    __shared__ float red[8][MB];             // 2.5 KB

    const int tid = threadIdx.x;
    const int wave = tid >> 6, lane = tid & 63;
    const int g = lane >> 4, ln = lane & 15;
    const int bid = blockIdx.x;
    const int m0 = bid * MB;

    // A staging role: threads 0..319 (waves 0..4, wave-uniform), one granule (gk, m) each
    const bool aRole = (tid < 320);
    const float *er = encp, *dr = decp;
    int agran = 0;
    if (aRole) {
        const int m = tid % MB;
        const int gk = tid / MB;
        const int mrow = m0 + m;
        const int b = mrow / (TT * UU);
        const int rem = mrow - b * (TT * UU);
        const int t = rem / UU;
        const int u = rem - t * UU;
        er = encp + (size_t)(b * TT + t) * DJ + gk * 8;
        dr = decp + (size_t)(b * UU + u) * DJ + gk * 8;
        agran = gk * MB + m;
    }

    f32x4 acc[5][8];
    #pragma unroll
    for (int mf = 0; mf < 5; ++mf)
        #pragma unroll
        for (int nf = 0; nf < 8; ++nf)
            acc[mf][nf] = (f32x4){0.f, 0.f, 0.f, 0.f};

    // ---- prologue: A(0) loads; B(0), B(1) issues; tanh A(0) -> As[0] ----
    {
        const int kb0 = bid & 31, kb1 = (bid + 1) & 31;
        float4 e0, e1, d0, d1;
        if (aRole) {
            const int ko = kb0 << 5;
            e0 = *(const float4*)(er + ko);
            e1 = *(const float4*)(er + ko + 4);
            d0 = *(const float4*)(dr + ko);
            d1 = *(const float4*)(dr + ko + 4);
        }
        const unsigned char* s0 = wfc8 + (size_t)kb0 * 32768;
        #pragma unroll
        for (int r = 0; r < 4; ++r)
            gload_lds16(s0 + (r * 512 + tid) * 16, &Bs[0][(r * 512 + tid) * 16]);
        const unsigned char* s1 = wfc8 + (size_t)kb1 * 32768;
        #pragma unroll
        for (int r = 0; r < 4; ++r)
            gload_lds16(s1 + (r * 512 + tid) * 16, &Bs[1][(r * 512 + tid) * 16]);
        if (aRole)
            *(unsigned long long*)&As[0][(size_t)agran * 8] = tanh_pack_fp8(e0, e1, d0, d1);
    }

    // ---- main loop: counted-vmcnt pipeline ----
    for (int t = 0; t < NITER; ++t) {
        const int cb = t % 3;
        // rendezvous: B(t) landed (B(t+1)'s 4 loads stay in flight), all LDS quiesced
        if (t < NITER - 1)
            asm volatile("s_waitcnt vmcnt(4) lgkmcnt(0)\n\ts_barrier" ::: "memory");
        else
            asm volatile("s_waitcnt vmcnt(0) lgkmcnt(0)\n\ts_barrier" ::: "memory");

        // issue A(t+1) globals (consumed by tanh at end of this iter)
        float4 e0, e1, d0, d1;
        const bool haveA = aRole && (t < NITER - 1);
        if (haveA) {
            const int ko = ((t + 1 + bid) & 31) << 5;
            e0 = *(const float4*)(er + ko);
            e1 = *(const float4*)(er + ko + 4);
            d0 = *(const float4*)(dr + ko);
            d1 = *(const float4*)(dr + ko + 4);
        }
        // issue B(t+2) gloads (Bs[(t+2)%3] last read at iter t-1: barrier-separated)
        if (t < NITER - 2) {
            const unsigned char* src = wfc8 + (size_t)((t + 2 + bid) & 31) * 32768;
            #pragma unroll
            for (int r = 0; r < 4; ++r)
                gload_lds16(src + (r * 512 + tid) * 16, &Bs[(t + 2) % 3][(r * 512 + tid) * 16]);
        }

        // MFMA on chunk t
        __builtin_amdgcn_s_setprio(1);
        long afr[5];
        #pragma unroll
        for (int mf = 0; mf < 5; ++mf)
            afr[mf] = *(const long*)&As[cb][(size_t)(g * MB + mf * 16 + ln) * 8];
        #pragma unroll
        for (int nf = 0; nf < 8; ++nf) {
            long bfr = *(const long*)&Bs[cb][(size_t)(g * 1024 + wave * 128 + nf * 16 + ln) * 8];
            #pragma unroll
            for (int mf = 0; mf < 5; ++mf)
                acc[mf][nf] = __builtin_amdgcn_mfma_f32_16x16x32_fp8_fp8(afr[mf], bfr, acc[mf][nf], 0, 0, 0);
        }
        __builtin_amdgcn_s_setprio(0);

        // tanh A(t+1) -> As[(t+1)%3] (readers hit it only after next barrier)
        if (haveA)
            *(unsigned long long*)&As[(t + 1) % 3][(size_t)agran * 8] = tanh_pack_fp8(e0, e1, d0, d1);
    }

    // ---- fused log_softmax epilogue ----
    // C frag (mf,nf): row = mf*16 + g*4 + j, col = wave*128 + nf*16 + ln
    float bv[8];
    #pragma unroll
    for (int nf = 0; nf < 8; ++nf) bv[nf] = bfc[wave * 128 + nf * 16 + ln];
    #pragma unroll
    for (int mf = 0; mf < 5; ++mf)
        #pragma unroll
        for (int nf = 0; nf < 8; ++nf)
            #pragma unroll
            for (int j = 0; j < 4; ++j)
                acc[mf][nf][j] = acc[mf][nf][j] * WINV + bv[nf];

    float rmx[5][4];
    #pragma unroll
    for (int mf = 0; mf < 5; ++mf)
        #pragma unroll
        for (int j = 0; j < 4; ++j) {
            float mx = -3.0e38f;
            #pragma unroll
            for (int nf = 0; nf < 8; ++nf) mx = fmaxf(mx, acc[mf][nf][j]);
            #pragma unroll
            for (int s = 1; s < 16; s <<= 1) mx = fmaxf(mx, __shfl_xor(mx, s));
            rmx[mf][j] = mx;
        }
    if (ln == 0) {
        #pragma unroll
        for (int mf = 0; mf < 5; ++mf)
            #pragma unroll
            for (int j = 0; j < 4; ++j)
                red[wave][mf * 16 + g * 4 + j] = rmx[mf][j];
    }
    __syncthreads();
    #pragma unroll
    for (int mf = 0; mf < 5; ++mf)
        #pragma unroll
        for (int j = 0; j < 4; ++j) {
            const int r = mf * 16 + g * 4 + j;
            float mx = red[0][r];
            #pragma unroll
            for (int w = 1; w < 8; ++w) mx = fmaxf(mx, red[w][r]);
            rmx[mf][j] = mx;
        }
    __syncthreads();   // red reused for sums

    float rsm[5][4];
    #pragma unroll
    for (int mf = 0; mf < 5; ++mf)
        #pragma unroll
        for (int j = 0; j < 4; ++j) {
            float s = 0.f;
            #pragma unroll
            for (int nf = 0; nf < 8; ++nf) s += __expf(acc[mf][nf][j] - rmx[mf][j]);
            #pragma unroll
            for (int t2 = 1; t2 < 16; t2 <<= 1) s += __shfl_xor(s, t2);
            rsm[mf][j] = s;
        }
    if (ln == 0) {
        #pragma unroll
        for (int mf = 0; mf < 5; ++mf)
            #pragma unroll
            for (int j = 0; j < 4; ++j)
                red[wave][mf * 16 + g * 4 + j] = rsm[mf][j];
    }
    __syncthreads();
    #pragma unroll
    for (int mf = 0; mf < 5; ++mf)
        #pragma unroll
        for (int j = 0; j < 4; ++j) {
            const int r = mf * 16 + g * 4 + j;
            float s = 0.f;
            #pragma unroll
            for (int w = 0; w < 8; ++w) s += red[w][r];
            const float lse = rmx[mf][j] + __logf(s);
            float* op = out + (size_t)(m0 + r) * VV + wave * 128 + ln;
            #pragma unroll
            for (int nf = 0; nf < 8; ++nf)
                __builtin_nontemporal_store(acc[mf][nf][j] - lse, op + nf * 16);
        }
}

extern "C" void kernel_launch(void* const* d_in, const int* in_sizes, int n_in,
                              void* d_out, int out_size, void* d_ws, size_t ws_size,
                              hipStream_t stream) {
    const float* enc   = (const float*)d_in[0];
    const float* dec   = (const float*)d_in[1];
    const float* W_enc = (const float*)d_in[2];
    const float* b_enc = (const float*)d_in[3];
    const float* W_dec = (const float*)d_in[4];
    const float* b_dec = (const float*)d_in[5];
    const float* W_fc  = (const float*)d_in[6];
    const float* b_fc  = (const float*)d_in[7];
    float* out = (float*)d_out;

    float* encp = (float*)d_ws;                              // 1600*1024 f32
    float* decp = encp + (size_t)BB * TT * DJ;               //  400*1024 f32
    unsigned char* wfc8 = (unsigned char*)(decp + (size_t)BB * UU * DJ);  // 1 MB fp8, granule-major

    k_wfct<<<(VV * DJ) / (256 * 8), 256, 0, stream>>>(W_fc, wfc8);
    k_proj2<<<dim3(125, DJ / 256), 256, 0, stream>>>(enc, dec, W_enc, b_enc, W_dec, b_dec, encp, decp);
    k_joint<<<M_TOTAL / MB, 512, 0, stream>>>(encp, decp, wfc8, b_fc, out);
}

// Round 8
// 373.800 us; speedup vs baseline: 10.7612x; 1.0755x over previous
//
#include <hip/hip_runtime.h>
#include <hip/hip_bf16.h>
#include <hip/hip_fp8.h>

#define TT 200
#define UU 50
#define BB 8
#define DJ 1024   // D_JOINT
#define DE 512    // D_ENC / D_DEC
#define VV 1024
#define M_TOTAL (BB*TT*UU)   // 80000
#define MB 80                // M rows per block
#define NITER 32             // K / 32
#define WINV (1.0f/32.0f)    // undo W_fc fp8 pre-scale

typedef float f32x4 __attribute__((ext_vector_type(4)));

__device__ __forceinline__ float fast_tanh(float x) {
    float e = __expf(2.f * x);
    return 1.f - 2.f / (e + 1.f);
}

__device__ __forceinline__ unsigned char f2fp8(float x) {
    return __hip_fp8_e4m3(x).__x;   // OCP e4m3, satfinite
}

__device__ __forceinline__ unsigned long long tanh_pack_fp8(float4 e0, float4 e1, float4 d0, float4 d1) {
    unsigned long long r;
    r  = (unsigned long long)f2fp8(fast_tanh(e0.x + d0.x));
    r |= (unsigned long long)f2fp8(fast_tanh(e0.y + d0.y)) << 8;
    r |= (unsigned long long)f2fp8(fast_tanh(e0.z + d0.z)) << 16;
    r |= (unsigned long long)f2fp8(fast_tanh(e0.w + d0.w)) << 24;
    r |= (unsigned long long)f2fp8(fast_tanh(e1.x + d1.x)) << 32;
    r |= (unsigned long long)f2fp8(fast_tanh(e1.y + d1.y)) << 40;
    r |= (unsigned long long)f2fp8(fast_tanh(e1.z + d1.z)) << 48;
    r |= (unsigned long long)f2fp8(fast_tanh(e1.w + d1.w)) << 56;
    return r;
}

__device__ __forceinline__ void gload_lds16(const unsigned char* g, unsigned char* l) {
    __builtin_amdgcn_global_load_lds(
        (const __attribute__((address_space(1))) unsigned int*)(const void*)g,
        (__attribute__((address_space(3))) unsigned int*)(void*)l, 16, 0, 0);
}

// ---------- kernel 1: W_fc fp32 [n][k] -> fp8 e4m3 (x32) granule-major [gk][n] ----------
__global__ void k_wfct(const float* __restrict__ w, unsigned char* __restrict__ o) {
    const int G = blockIdx.x * 256 + threadIdx.x;   // 131072 granules
    const int gk = G >> 10, n = G & 1023;
    const float* src = w + (size_t)n * DJ + gk * 8;
    float4 a = *(const float4*)(src);
    float4 b = *(const float4*)(src + 4);
    unsigned long long r;
    r  = (unsigned long long)f2fp8(a.x * 32.f);
    r |= (unsigned long long)f2fp8(a.y * 32.f) << 8;
    r |= (unsigned long long)f2fp8(a.z * 32.f) << 16;
    r |= (unsigned long long)f2fp8(a.w * 32.f) << 24;
    r |= (unsigned long long)f2fp8(b.x * 32.f) << 32;
    r |= (unsigned long long)f2fp8(b.y * 32.f) << 40;
    r |= (unsigned long long)f2fp8(b.z * 32.f) << 48;
    r |= (unsigned long long)f2fp8(b.w * 32.f) << 56;
    *(unsigned long long*)(o + (size_t)G * 8) = r;
}

// ---------- kernel 2: projections -> GRANULE-MAJOR f32 [gk][rows][8] ----------
__global__ __launch_bounds__(256) void k_proj2(const float* __restrict__ enc,
                                               const float* __restrict__ dec,
                                               const float* __restrict__ W_enc,
                                               const float* __restrict__ b_enc,
                                               const float* __restrict__ W_dec,
                                               const float* __restrict__ b_dec,
                                               float* __restrict__ encp,
                                               float* __restrict__ decp) {
    __shared__ float in_s[16][DE];
    const bool isDec = blockIdx.x >= 100;
    const float* in  = isDec ? dec   : enc;
    const float* W   = isDec ? W_dec : W_enc;
    const float* bia = isDec ? b_dec : b_enc;
    float* out       = isDec ? decp  : encp;
    const int NR     = isDec ? (BB*UU) : (BB*TT);
    const int m0 = (isDec ? (blockIdx.x - 100) : blockIdx.x) * 16;
    const int tid = threadIdx.x;
    #pragma unroll
    for (int it = 0; it < 8; ++it) {
        int idx = tid + it * 256;
        int r = idx >> 7, c = (idx & 127) << 2;
        *(float4*)&in_s[r][c] = *(const float4*)(in + (size_t)(m0 + r) * DE + c);
    }
    __syncthreads();
    const int j = blockIdx.y * 256 + tid;
    const float4* wr = (const float4*)(W + (size_t)j * DE);
    float acc[16];
    #pragma unroll
    for (int r = 0; r < 16; ++r) acc[r] = 0.f;
    for (int d4 = 0; d4 < DE / 4; ++d4) {
        float4 w = wr[d4];
        #pragma unroll
        for (int r = 0; r < 16; ++r) {
            float4 x = *(const float4*)&in_s[r][d4 << 2];
            acc[r] += x.x * w.x + x.y * w.y + x.z * w.z + x.w * w.w;
        }
    }
    float bv = bia[j];
    const int gk = j >> 3, kl = j & 7;
    #pragma unroll
    for (int r = 0; r < 16; ++r)
        out[((size_t)gk * NR + (m0 + r)) * 8 + kl] = acc[r] + bv;
}

// ---------- kernel 3: fused tanh(enc+dec) @ W_fc^T + b_fc -> log_softmax ----------
// 512 threads (8 waves). Block: 80 M x 1024 N, fp8 GEMM.
// Prologue: compute full A-stripe (tanh->fp8, 80 KB) into LDS; issue B(0) DMA first.
// Main loop: 4-phase schedule per 32KB K-chunk (T3+T4+T5):
//   top: issue gload#0(t+1); s_waitcnt vmcnt(1) [counted]; barrier
//   phase p: ds_read B-pair (+A in p0); issue gload#(p+1)(t+1); barrier;
//            lgkmcnt(0)+sched_barrier; setprio(1); 10 MFMA; setprio(0); barrier
__global__ __launch_bounds__(512, 2) void k_joint(const float* __restrict__ encp,
                                                  const float* __restrict__ decp,
                                                  const unsigned char* __restrict__ wfc8,
                                                  const float* __restrict__ bfc,
                                                  float* __restrict__ out) {
    __shared__ unsigned char As[81920];      // 80 KB: granule (gkfull 0..127, m 0..79)
    __shared__ unsigned char Bs[2][32768];   // 64 KB: [g 0..3][n 0..1023] 8B granules
    __shared__ float red[8][MB];             // 2.5 KB

    const int tid = threadIdx.x;
    const int wave = tid >> 6, lane = tid & 63;
    const int g = lane >> 4, ln = lane & 15;
    const int bid = blockIdx.x;
    const int m0 = bid * MB;

    // ---- prologue: B(0) DMA first, then compute A-stripe into LDS ----
    {
        const unsigned char* s0 = wfc8 + (size_t)(bid & 31) * 32768;
        #pragma unroll
        for (int r = 0; r < 4; ++r)
            gload_lds16(s0 + (r * 512 + tid) * 16, &Bs[0][(r * 512 + tid) * 16]);
    }
    for (int r = 0; r < 20; ++r) {
        const int gidx = r * 512 + tid;          // 10240 granules: gkf*80 + m
        const int gkf = gidx / MB;
        const int m = gidx - gkf * MB;
        const int mrow = m0 + m;
        const int b = mrow / (TT * UU);
        const int rem = mrow - b * (TT * UU);
        const int t = rem / UU;
        const int u = rem - t * UU;
        const float* ep = encp + ((size_t)gkf * (BB * TT) + b * TT + t) * 8;
        const float* dp = decp + ((size_t)gkf * (BB * UU) + b * UU + u) * 8;
        float4 e0 = *(const float4*)(ep);
        float4 e1 = *(const float4*)(ep + 4);
        float4 d0 = *(const float4*)(dp);
        float4 d1 = *(const float4*)(dp + 4);
        *(unsigned long long*)&As[(size_t)gidx * 8] = tanh_pack_fp8(e0, e1, d0, d1);
    }

    f32x4 acc[5][8];
    #pragma unroll
    for (int mf = 0; mf < 5; ++mf)
        #pragma unroll
        for (int nf = 0; nf < 8; ++nf)
            acc[mf][nf] = (f32x4){0.f, 0.f, 0.f, 0.f};

    // ---- main loop ----
    for (int t = 0; t < NITER; ++t) {
        const int cur = t & 1, nxt = cur ^ 1;
        const int kb = (t + bid) & 31;
        const unsigned char* srcN = wfc8 + (size_t)((t + 1 + bid) & 31) * 32768;
        // top-of-chunk rendezvous (safe: previous chunk's last barrier precedes)
        if (t < NITER - 1) {
            gload_lds16(srcN + (size_t)tid * 16, &Bs[nxt][(size_t)tid * 16]);
            asm volatile("s_waitcnt vmcnt(1) lgkmcnt(0)" ::: "memory");
        } else {
            asm volatile("s_waitcnt vmcnt(0) lgkmcnt(0)" ::: "memory");
        }
        __builtin_amdgcn_sched_barrier(0);
        __builtin_amdgcn_s_barrier();

        long afr[5];
        #pragma unroll
        for (int ph = 0; ph < 4; ++ph) {
            if (ph == 0) {
                #pragma unroll
                for (int mf = 0; mf < 5; ++mf)
                    afr[mf] = *(const long*)&As[(size_t)((kb * 4 + g) * MB + mf * 16 + ln) * 8];
            }
            long bfr[2];
            #pragma unroll
            for (int q = 0; q < 2; ++q)
                bfr[q] = *(const long*)&Bs[cur][(size_t)(g * 1024 + wave * 128 + (ph * 2 + q) * 16 + ln) * 8];
            if (t < NITER - 1 && ph < 3)
                gload_lds16(srcN + (size_t)((ph + 1) * 512 + tid) * 16,
                            &Bs[nxt][(size_t)((ph + 1) * 512 + tid) * 16]);
            __builtin_amdgcn_sched_barrier(0);
            __builtin_amdgcn_s_barrier();
            asm volatile("s_waitcnt lgkmcnt(0)" ::: "memory");
            __builtin_amdgcn_sched_barrier(0);
            __builtin_amdgcn_s_setprio(1);
            #pragma unroll
            for (int q = 0; q < 2; ++q)
                #pragma unroll
                for (int mf = 0; mf < 5; ++mf)
                    acc[mf][ph * 2 + q] = __builtin_amdgcn_mfma_f32_16x16x32_fp8_fp8(afr[mf], bfr[q], acc[mf][ph * 2 + q], 0, 0, 0);
            __builtin_amdgcn_s_setprio(0);
            __builtin_amdgcn_sched_barrier(0);
            __builtin_amdgcn_s_barrier();
        }
    }

    // ---- fused log_softmax epilogue ----
    // C frag (mf,nf): row = mf*16 + g*4 + j, col = wave*128 + nf*16 + ln
    float bv[8];
    #pragma unroll
    for (int nf = 0; nf < 8; ++nf) bv[nf] = bfc[wave * 128 + nf * 16 + ln];
    #pragma unroll
    for (int mf = 0; mf < 5; ++mf)
        #pragma unroll
        for (int nf = 0; nf < 8; ++nf)
            #pragma unroll
            for (int j = 0; j < 4; ++j)
                acc[mf][nf][j] = acc[mf][nf][j] * WINV + bv[nf];

    float rmx[5][4];
    #pragma unroll
    for (int mf = 0; mf < 5; ++mf)
        #pragma unroll
        for (int j = 0; j < 4; ++j) {
            float mx = -3.0e38f;
            #pragma unroll
            for (int nf = 0; nf < 8; ++nf) mx = fmaxf(mx, acc[mf][nf][j]);
            #pragma unroll
            for (int s = 1; s < 16; s <<= 1) mx = fmaxf(mx, __shfl_xor(mx, s));
            rmx[mf][j] = mx;
        }
    if (ln == 0) {
        #pragma unroll
        for (int mf = 0; mf < 5; ++mf)
            #pragma unroll
            for (int j = 0; j < 4; ++j)
                red[wave][mf * 16 + g * 4 + j] = rmx[mf][j];
    }
    __syncthreads();
    #pragma unroll
    for (int mf = 0; mf < 5; ++mf)
        #pragma unroll
        for (int j = 0; j < 4; ++j) {
            const int r = mf * 16 + g * 4 + j;
            float mx = red[0][r];
            #pragma unroll
            for (int w = 1; w < 8; ++w) mx = fmaxf(mx, red[w][r]);
            rmx[mf][j] = mx;
        }
    __syncthreads();   // red reused for sums

    float rsm[5][4];
    #pragma unroll
    for (int mf = 0; mf < 5; ++mf)
        #pragma unroll
        for (int j = 0; j < 4; ++j) {
            float s = 0.f;
            #pragma unroll
            for (int nf = 0; nf < 8; ++nf) s += __expf(acc[mf][nf][j] - rmx[mf][j]);
            #pragma unroll
            for (int t2 = 1; t2 < 16; t2 <<= 1) s += __shfl_xor(s, t2);
            rsm[mf][j] = s;
        }
    if (ln == 0) {
        #pragma unroll
        for (int mf = 0; mf < 5; ++mf)
            #pragma unroll
            for (int j = 0; j < 4; ++j)
                red[wave][mf * 16 + g * 4 + j] = rsm[mf][j];
    }
    __syncthreads();
    #pragma unroll
    for (int mf = 0; mf < 5; ++mf)
        #pragma unroll
        for (int j = 0; j < 4; ++j) {
            const int r = mf * 16 + g * 4 + j;
            float s = 0.f;
            #pragma unroll
            for (int w = 0; w < 8; ++w) s += red[w][r];
            const float lse = rmx[mf][j] + __logf(s);
            float* op = out + (size_t)(m0 + r) * VV + wave * 128 + ln;
            #pragma unroll
            for (int nf = 0; nf < 8; ++nf)
                __builtin_nontemporal_store(acc[mf][nf][j] - lse, op + nf * 16);
        }
}

extern "C" void kernel_launch(void* const* d_in, const int* in_sizes, int n_in,
                              void* d_out, int out_size, void* d_ws, size_t ws_size,
                              hipStream_t stream) {
    const float* enc   = (const float*)d_in[0];
    const float* dec   = (const float*)d_in[1];
    const float* W_enc = (const float*)d_in[2];
    const float* b_enc = (const float*)d_in[3];
    const float* W_dec = (const float*)d_in[4];
    const float* b_dec = (const float*)d_in[5];
    const float* W_fc  = (const float*)d_in[6];
    const float* b_fc  = (const float*)d_in[7];
    float* out = (float*)d_out;

    float* encp = (float*)d_ws;                               // 1600*1024 f32, granule-major
    float* decp = encp + (size_t)BB * TT * DJ;                //  400*1024 f32, granule-major
    unsigned char* wfc8 = (unsigned char*)(decp + (size_t)BB * UU * DJ);  // 1 MB fp8, granule-major
    // total ws: 9.2 MB (same footprint as passing rounds 1-6)

    k_wfct<<<(VV * DJ) / (256 * 8), 256, 0, stream>>>(W_fc, wfc8);
    k_proj2<<<dim3(125, DJ / 256), 256, 0, stream>>>(enc, dec, W_enc, b_enc, W_dec, b_dec, encp, decp);
    k_joint<<<M_TOTAL / MB, 512, 0, stream>>>(encp, decp, wfc8, b_fc, out);
}

// Round 9
// 325.684 us; speedup vs baseline: 12.3510x; 1.1477x over previous
//
#include <hip/hip_runtime.h>
#include <hip/hip_bf16.h>
#include <hip/hip_fp8.h>

#define TT 200
#define UU 50
#define BB 8
#define DJ 1024   // D_JOINT
#define DE 512    // D_ENC / D_DEC
#define VV 1024
#define M_TOTAL (BB*TT*UU)   // 80000
#define MB 80                // M rows per block
#define NITER 32             // K / 32
#define WINV (1.0f/32.0f)    // undo W_fc fp8 pre-scale

typedef float f32x4 __attribute__((ext_vector_type(4)));

__device__ __forceinline__ float fast_tanh(float x) {
    float e = __expf(2.f * x);
    return 1.f - 2.f / (e + 1.f);
}

__device__ __forceinline__ unsigned char f2fp8(float x) {
    return __hip_fp8_e4m3(x).__x;   // OCP e4m3, satfinite
}

__device__ __forceinline__ unsigned long long tanh_pack_fp8(float4 e0, float4 e1, float4 d0, float4 d1) {
    unsigned long long r;
    r  = (unsigned long long)f2fp8(fast_tanh(e0.x + d0.x));
    r |= (unsigned long long)f2fp8(fast_tanh(e0.y + d0.y)) << 8;
    r |= (unsigned long long)f2fp8(fast_tanh(e0.z + d0.z)) << 16;
    r |= (unsigned long long)f2fp8(fast_tanh(e0.w + d0.w)) << 24;
    r |= (unsigned long long)f2fp8(fast_tanh(e1.x + d1.x)) << 32;
    r |= (unsigned long long)f2fp8(fast_tanh(e1.y + d1.y)) << 40;
    r |= (unsigned long long)f2fp8(fast_tanh(e1.z + d1.z)) << 48;
    r |= (unsigned long long)f2fp8(fast_tanh(e1.w + d1.w)) << 56;
    return r;
}

// ---------- kernel 1: W_fc fp32 [n][k] -> fp8 e4m3 (x32) granule-major [gk][n] ----------
__global__ void k_wfct(const float* __restrict__ w, unsigned char* __restrict__ o) {
    const int G = blockIdx.x * 256 + threadIdx.x;   // 131072 granules
    const int gk = G >> 10, n = G & 1023;
    const float* src = w + (size_t)n * DJ + gk * 8;
    float4 a = *(const float4*)(src);
    float4 b = *(const float4*)(src + 4);
    unsigned long long r;
    r  = (unsigned long long)f2fp8(a.x * 32.f);
    r |= (unsigned long long)f2fp8(a.y * 32.f) << 8;
    r |= (unsigned long long)f2fp8(a.z * 32.f) << 16;
    r |= (unsigned long long)f2fp8(a.w * 32.f) << 24;
    r |= (unsigned long long)f2fp8(b.x * 32.f) << 32;
    r |= (unsigned long long)f2fp8(b.y * 32.f) << 40;
    r |= (unsigned long long)f2fp8(b.z * 32.f) << 48;
    r |= (unsigned long long)f2fp8(b.w * 32.f) << 56;
    *(unsigned long long*)(o + (size_t)G * 8) = r;
}

// ---------- kernel 2: projections -> GRANULE-MAJOR f32 [gk][rows][8] ----------
__global__ __launch_bounds__(256) void k_proj2(const float* __restrict__ enc,
                                               const float* __restrict__ dec,
                                               const float* __restrict__ W_enc,
                                               const float* __restrict__ b_enc,
                                               const float* __restrict__ W_dec,
                                               const float* __restrict__ b_dec,
                                               float* __restrict__ encp,
                                               float* __restrict__ decp) {
    __shared__ float in_s[16][DE];
    const bool isDec = blockIdx.x >= 100;
    const float* in  = isDec ? dec   : enc;
    const float* W   = isDec ? W_dec : W_enc;
    const float* bia = isDec ? b_dec : b_enc;
    float* out       = isDec ? decp  : encp;
    const int NR     = isDec ? (BB*UU) : (BB*TT);
    const int m0 = (isDec ? (blockIdx.x - 100) : blockIdx.x) * 16;
    const int tid = threadIdx.x;
    #pragma unroll
    for (int it = 0; it < 8; ++it) {
        int idx = tid + it * 256;
        int r = idx >> 7, c = (idx & 127) << 2;
        *(float4*)&in_s[r][c] = *(const float4*)(in + (size_t)(m0 + r) * DE + c);
    }
    __syncthreads();
    const int j = blockIdx.y * 256 + tid;
    const float4* wr = (const float4*)(W + (size_t)j * DE);
    float acc[16];
    #pragma unroll
    for (int r = 0; r < 16; ++r) acc[r] = 0.f;
    for (int d4 = 0; d4 < DE / 4; ++d4) {
        float4 w = wr[d4];
        #pragma unroll
        for (int r = 0; r < 16; ++r) {
            float4 x = *(const float4*)&in_s[r][d4 << 2];
            acc[r] += x.x * w.x + x.y * w.y + x.z * w.z + x.w * w.w;
        }
    }
    float bv = bia[j];
    const int gk = j >> 3, kl = j & 7;
    #pragma unroll
    for (int r = 0; r < 16; ++r)
        out[((size_t)gk * NR + (m0 + r)) * 8 + kl] = acc[r] + bv;
}

// ---------- kernel 3: fused tanh(enc+dec) @ W_fc^T + b_fc -> log_softmax ----------
// 512 threads (8 waves). Block: 80 M x 1024 N, fp8 GEMM.
// Prologue: compute A-stripe (tanh->fp8, 80 KB) into LDS; ONE barrier.
// Main loop: BARRIER-FREE. Each wave owns a 128-col N-slice and loads its B
// fragments global->reg (coalesced 128B segments, L2-resident W_fc); A from LDS.
// Waves free-run; the compiler pipelines loads across iterations.
__global__ __launch_bounds__(512, 2) void k_joint(const float* __restrict__ encp,
                                                  const float* __restrict__ decp,
                                                  const unsigned char* __restrict__ wfc8,
                                                  const float* __restrict__ bfc,
                                                  float* __restrict__ out) {
    __shared__ unsigned char As[81920];      // 80 KB: granule (gkf 0..127, m 0..79)
    __shared__ float red[8][MB];             // 2.5 KB

    const int tid = threadIdx.x;
    const int wave = tid >> 6, lane = tid & 63;
    const int g = lane >> 4, ln = lane & 15;
    const int bid = blockIdx.x;
    const int m0 = bid * MB;

    // ---- prologue: compute A-stripe into LDS ----
    for (int r = 0; r < 20; ++r) {
        const int gidx = r * 512 + tid;          // 10240 granules: gkf*80 + m
        const int gkf = gidx / MB;
        const int m = gidx - gkf * MB;
        const int mrow = m0 + m;
        const int b = mrow / (TT * UU);
        const int rem = mrow - b * (TT * UU);
        const int t = rem / UU;
        const int u = rem - t * UU;
        const float* ep = encp + ((size_t)gkf * (BB * TT) + b * TT + t) * 8;
        const float* dp = decp + ((size_t)gkf * (BB * UU) + b * UU + u) * 8;
        float4 e0 = *(const float4*)(ep);
        float4 e1 = *(const float4*)(ep + 4);
        float4 d0 = *(const float4*)(dp);
        float4 d1 = *(const float4*)(dp + 4);
        *(unsigned long long*)&As[(size_t)gidx * 8] = tanh_pack_fp8(e0, e1, d0, d1);
    }

    f32x4 acc[5][8];
    #pragma unroll
    for (int mf = 0; mf < 5; ++mf)
        #pragma unroll
        for (int nf = 0; nf < 8; ++nf)
            acc[mf][nf] = (f32x4){0.f, 0.f, 0.f, 0.f};

    __syncthreads();   // As ready; the ONLY main-path barrier

    // per-wave B base: granule (gk, n) at wfc8 + (gk*1024 + n)*8
    const unsigned char* bbase = wfc8 + (size_t)(wave * 128 + ln) * 8;

    // ---- main loop: barrier-free, free-running waves ----
    for (int t = 0; t < NITER; ++t) {
        const int kb = (t + bid) & 31;           // stagger spreads L2 addresses
        long afr[5];
        #pragma unroll
        for (int mf = 0; mf < 5; ++mf)
            afr[mf] = *(const long*)&As[(size_t)((kb * 4 + g) * MB + mf * 16 + ln) * 8];
        const unsigned char* bchunk = bbase + (size_t)(kb * 4 + g) * 1024 * 8;
        #pragma unroll
        for (int nf = 0; nf < 8; ++nf) {
            long bfr = *(const long*)(bchunk + (size_t)nf * 16 * 8);
            #pragma unroll
            for (int mf = 0; mf < 5; ++mf)
                acc[mf][nf] = __builtin_amdgcn_mfma_f32_16x16x32_fp8_fp8(afr[mf], bfr, acc[mf][nf], 0, 0, 0);
        }
    }

    // ---- fused log_softmax epilogue ----
    // C frag (mf,nf): row = mf*16 + g*4 + j, col = wave*128 + nf*16 + ln
    float bv[8];
    #pragma unroll
    for (int nf = 0; nf < 8; ++nf) bv[nf] = bfc[wave * 128 + nf * 16 + ln];
    #pragma unroll
    for (int mf = 0; mf < 5; ++mf)
        #pragma unroll
        for (int nf = 0; nf < 8; ++nf)
            #pragma unroll
            for (int j = 0; j < 4; ++j)
                acc[mf][nf][j] = acc[mf][nf][j] * WINV + bv[nf];

    float rmx[5][4];
    #pragma unroll
    for (int mf = 0; mf < 5; ++mf)
        #pragma unroll
        for (int j = 0; j < 4; ++j) {
            float mx = -3.0e38f;
            #pragma unroll
            for (int nf = 0; nf < 8; ++nf) mx = fmaxf(mx, acc[mf][nf][j]);
            #pragma unroll
            for (int s = 1; s < 16; s <<= 1) mx = fmaxf(mx, __shfl_xor(mx, s));
            rmx[mf][j] = mx;
        }
    if (ln == 0) {
        #pragma unroll
        for (int mf = 0; mf < 5; ++mf)
            #pragma unroll
            for (int j = 0; j < 4; ++j)
                red[wave][mf * 16 + g * 4 + j] = rmx[mf][j];
    }
    __syncthreads();
    #pragma unroll
    for (int mf = 0; mf < 5; ++mf)
        #pragma unroll
        for (int j = 0; j < 4; ++j) {
            const int r = mf * 16 + g * 4 + j;
            float mx = red[0][r];
            #pragma unroll
            for (int w = 1; w < 8; ++w) mx = fmaxf(mx, red[w][r]);
            rmx[mf][j] = mx;
        }
    __syncthreads();   // red reused for sums

    float rsm[5][4];
    #pragma unroll
    for (int mf = 0; mf < 5; ++mf)
        #pragma unroll
        for (int j = 0; j < 4; ++j) {
            float s = 0.f;
            #pragma unroll
            for (int nf = 0; nf < 8; ++nf) s += __expf(acc[mf][nf][j] - rmx[mf][j]);
            #pragma unroll
            for (int t2 = 1; t2 < 16; t2 <<= 1) s += __shfl_xor(s, t2);
            rsm[mf][j] = s;
        }
    if (ln == 0) {
        #pragma unroll
        for (int mf = 0; mf < 5; ++mf)
            #pragma unroll
            for (int j = 0; j < 4; ++j)
                red[wave][mf * 16 + g * 4 + j] = rsm[mf][j];
    }
    __syncthreads();
    #pragma unroll
    for (int mf = 0; mf < 5; ++mf)
        #pragma unroll
        for (int j = 0; j < 4; ++j) {
            const int r = mf * 16 + g * 4 + j;
            float s = 0.f;
            #pragma unroll
            for (int w = 0; w < 8; ++w) s += red[w][r];
            const float lse = rmx[mf][j] + __logf(s);
            float* op = out + (size_t)(m0 + r) * VV + wave * 128 + ln;
            #pragma unroll
            for (int nf = 0; nf < 8; ++nf)
                __builtin_nontemporal_store(acc[mf][nf][j] - lse, op + nf * 16);
        }
}

extern "C" void kernel_launch(void* const* d_in, const int* in_sizes, int n_in,
                              void* d_out, int out_size, void* d_ws, size_t ws_size,
                              hipStream_t stream) {
    const float* enc   = (const float*)d_in[0];
    const float* dec   = (const float*)d_in[1];
    const float* W_enc = (const float*)d_in[2];
    const float* b_enc = (const float*)d_in[3];
    const float* W_dec = (const float*)d_in[4];
    const float* b_dec = (const float*)d_in[5];
    const float* W_fc  = (const float*)d_in[6];
    const float* b_fc  = (const float*)d_in[7];
    float* out = (float*)d_out;

    float* encp = (float*)d_ws;                               // 1600*1024 f32, granule-major
    float* decp = encp + (size_t)BB * TT * DJ;                //  400*1024 f32, granule-major
    unsigned char* wfc8 = (unsigned char*)(decp + (size_t)BB * UU * DJ);  // 1 MB fp8, granule-major
    // total ws: 9.2 MB (same footprint as passing rounds)

    k_wfct<<<(VV * DJ) / (256 * 8), 256, 0, stream>>>(W_fc, wfc8);
    k_proj2<<<dim3(125, DJ / 256), 256, 0, stream>>>(enc, dec, W_enc, b_enc, W_dec, b_dec, encp, decp);
    k_joint<<<M_TOTAL / MB, 512, 0, stream>>>(encp, decp, wfc8, b_fc, out);
}